// Round 10
// baseline (2155.819 us; speedup 1.0000x reference)
//
#include <hip/hip_runtime.h>
#include <stdint.h>

typedef unsigned short u16;
typedef short bf16x8 __attribute__((ext_vector_type(8)));
typedef float f32x4 __attribute__((ext_vector_type(4)));

#define CTX 2048
#define DIN 1024
#define DOUT 1024
#define NB 8

__device__ __forceinline__ u16 f2bf(float f) {
  uint32_t u = __builtin_bit_cast(uint32_t, f);
  u += 0x7FFFu + ((u >> 16) & 1u);
  return (u16)(u >> 16);
}

// global -> LDS async, 16B per lane. LDS dest is wave-uniform base + lane*16.
__device__ __forceinline__ void gld_lds16(const u16* g, const u16* lds) {
  __builtin_amdgcn_global_load_lds(
      (const __attribute__((address_space(1))) uint32_t*)(unsigned long long)(const void*)g,
      (__attribute__((address_space(3))) uint32_t*)(uint32_t)(unsigned long long)(const void*)lds,
      16, 0, 0);
}

#define SBAR() asm volatile("s_barrier" ::: "memory")
#define VMCNT0() asm volatile("s_waitcnt vmcnt(0)" ::: "memory")
#define SCHED0() __builtin_amdgcn_sched_barrier(0)

// ---------------------------------------------------------------------------
// 256x256-tile GEMM, bf16, BK=32, DOUBLE-buffered LDS (64 KB) -> 2 blocks/CU.
// ROUND-10 KEY CHANGE: rounds 4-9 used 96-128 KB LDS => ONE block/CU = 2
// waves/SIMD; the per-wave serial chain (ds_read -> lgkm -> in-order MFMA
// burst) had nothing to hide behind, pinning MfmaUtil at 33% regardless of
// intra-block schedule (six variants identical). 64 KB => 2 independent
// blocks co-resident per CU (16 waves, 4/SIMD); one block's MFMA burst
// overlaps the other block's DS/stage phase in hardware (m114 co-scheduling,
// the m97 implicit-overlap mechanism).
// Body per K-tile T: {STAGE(T+1)->buf[T^1]; 12 ds_read buf[T&1]; 32 MFMA;
// sched_barrier(0); vmcnt(0); s_barrier}.
// Safety: stage targets the non-live buffer (last read tile T-1, behind that
// tile's barrier). ds_read completion before the barrier is enforced by the
// compiler's lgkm waits on the consuming MFMAs; SCHED0 pins the MFMA cluster
// (register-only, could sink past "memory" asm -- rule 18) above vmcnt/bar.
// vmcnt(0) waits a stage issued ~2000 cy earlier -> ~free.
// VGPR=128 -> 16 waves/CU allowed; LDS 2 x 64 KB = 128 KB/CU fits.
// Accumulation order: ascending 32-k chunks == rounds 4-9 (bitwise identical).
// Requires nkt >= 1.
// ---------------------------------------------------------------------------
template <typename EPI>
__device__ __forceinline__ void gemm256(const u16* __restrict__ A, int lda,
                                        const u16* __restrict__ Bt, int ldb,
                                        int m0, int n0, int K, EPI&& epi) {
  __shared__ __align__(16) u16 lds[32768];  // 2 x [A 8192 | B 8192] u16 = 64 KB

  const int t = threadIdx.x;
  const int lane = t & 63;
  const int w = t >> 6;     // 0..7
  const int wm = w >> 2;    // 0..1 (m half)
  const int wn = w & 3;     // 0..3 (n col group)
  const int l15 = lane & 15;
  const int l16 = lane >> 4;
  const int nkt = K >> 5;   // BK = 32

  f32x4 acc[8][4];
#pragma unroll
  for (int i = 0; i < 8; ++i)
#pragma unroll
    for (int j = 0; j < 4; ++j) acc[i][j] = {0.f, 0.f, 0.f, 0.f};

  // staging: gld j covers rows [j*128, j*128+128): wave w -> 16-row block w
  const u16* gA = A + (size_t)(m0 + w * 16 + l15) * lda + l16 * 8;
  const u16* gB = Bt + (size_t)(n0 + w * 16 + l15) * ldb + l16 * 8;
  const size_t ldJA = (size_t)128 * lda;
  const size_t ldJB = (size_t)128 * ldb;

  auto STAGE = [&](int kbuf, int T) {  // 4 gld_lds16: full 32KB tile T
    const size_t koff = (size_t)T * 32;
    u16* base = lds + kbuf * 16384;
    gld_lds16(gA + koff, base + w * 512);                  // A rows 0..127
    gld_lds16(gA + koff + ldJA, base + 4096 + w * 512);    // A rows 128..255
    gld_lds16(gB + koff, base + 8192 + w * 512);           // B rows 0..127
    gld_lds16(gB + koff + ldJB, base + 12288 + w * 512);   // B rows 128..255
  };

  // prologue: tile 0 into buf0, landed before first reads
  STAGE(0, 0);
  VMCNT0();
  SBAR();

  for (int T = 0; T < nkt; ++T) {
    const int cb = T & 1;
    // prefetch next tile into the non-live buffer (last read in tile T-1)
    if (T + 1 < nkt) STAGE(cb ^ 1, T + 1);

    const u16* bufA = lds + cb * 16384 + (wm * 8) * 512 + lane * 8;
    const u16* bufB = lds + cb * 16384 + 8192 + (wn * 4) * 512 + lane * 8;
    bf16x8 ar[8], br[4];
#pragma unroll
    for (int fr = 0; fr < 8; ++fr)
      ar[fr] = *reinterpret_cast<const bf16x8*>(bufA + fr * 512);
#pragma unroll
    for (int nc = 0; nc < 4; ++nc)
      br[nc] = *reinterpret_cast<const bf16x8*>(bufB + nc * 512);

    __builtin_amdgcn_s_setprio(1);
#pragma unroll
    for (int fr = 0; fr < 8; ++fr)
#pragma unroll
      for (int nc = 0; nc < 4; ++nc)
        acc[fr][nc] = __builtin_amdgcn_mfma_f32_16x16x32_bf16(ar[fr], br[nc],
                                                              acc[fr][nc], 0, 0, 0);
    __builtin_amdgcn_s_setprio(0);
    SCHED0();  // pin MFMAs + their lgkm waits above the vmcnt/barrier (rule 18)
    VMCNT0();  // stage(T+1) (issued ~2000 cy ago) landed
    SBAR();
  }

  // epilogue: row = r0 + fr*16 + i, col = c0 + nc*16 (tile-local)
  epi(acc, wm * 128 + l16 * 4, wn * 64 + l15);
}

// ---------------------------------------------------------------------------
__global__ __launch_bounds__(256) void k_cvt_x(const float* __restrict__ x,
                                               u16* __restrict__ xb) {
  const int idx = (blockIdx.x * 256 + threadIdx.x) * 4;
  const float4 v = *reinterpret_cast<const float4*>(x + idx);
  ushort4 o;
  o.x = f2bf(v.x); o.y = f2bf(v.y); o.z = f2bf(v.z); o.w = f2bf(v.w);
  *reinterpret_cast<ushort4*>(xb + idx) = o;
}

// W [DIN][DOUT] fp32 -> Wt [DOUT][DIN] bf16 (tiled transpose via LDS)
__global__ __launch_bounds__(256) void k_cvt_wt(const float* __restrict__ W,
                                                u16* __restrict__ Wt) {
  __shared__ u16 tile[64][65];
  const int bc = blockIdx.x;
  const int tr0 = (bc >> 4) * 64;
  const int tc0 = (bc & 15) * 64;
  const int t = threadIdx.x;
  const int col = t & 63, rr = t >> 6;
#pragma unroll
  for (int p = 0; p < 16; ++p) {
    const int row = rr * 16 + p;
    tile[row][col] = f2bf(W[(size_t)(tr0 + row) * DOUT + tc0 + col]);
  }
  __syncthreads();
#pragma unroll
  for (int p = 0; p < 16; ++p) {
    const int row = rr * 16 + p;
    Wt[(size_t)(tc0 + row) * DIN + tr0 + col] = tile[col][row];
  }
}

// Fused QKV projection. 768 blocks, XCD-swizzled; n-tiles 0-7 -> qk row-major,
// 8-11 -> vT transposed.
__global__ __launch_bounds__(512, 4) void k_proj(const u16* __restrict__ xb,
                                                 const u16* __restrict__ Wt,
                                                 u16* __restrict__ qkb,
                                                 u16* __restrict__ vT) {
  const int wg = (blockIdx.x & 7) * 96 + (blockIdx.x >> 3);  // bijective, 768%8==0
  const int m0 = (wg / 12) * 256, n0 = (wg % 12) * 256;
  gemm256(xb, DIN, Wt, DIN, m0, n0, DIN,
          [&](const f32x4(&acc)[8][4], int r0, int c0) {
            if (n0 < 2 * DOUT) {  // q or k -> qkb row-major [16384][2048]
#pragma unroll
              for (int fr = 0; fr < 8; ++fr)
#pragma unroll
                for (int nc = 0; nc < 4; ++nc) {
                  const int r = m0 + r0 + fr * 16;
                  const int c = n0 + c0 + nc * 16;
#pragma unroll
                  for (int i = 0; i < 4; ++i)
                    qkb[(size_t)(r + i) * 2048 + c] = f2bf(acc[fr][nc][i]);
                }
            } else {  // v -> vT[b][d][s]
              const int b = m0 >> 11;
              const int sl = (m0 & (CTX - 1)) + r0;
              u16* C = vT + (size_t)b * DOUT * CTX;
#pragma unroll
              for (int fr = 0; fr < 8; ++fr)
#pragma unroll
                for (int nc = 0; nc < 4; ++nc) {
                  const int d = n0 - 2 * DOUT + c0 + nc * 16;
                  const int s = sl + fr * 16;
                  ushort4 o;
                  o.x = f2bf(acc[fr][nc][0]);
                  o.y = f2bf(acc[fr][nc][1]);
                  o.z = f2bf(acc[fr][nc][2]);
                  o.w = f2bf(acc[fr][nc][3]);
                  *reinterpret_cast<ushort4*>(C + (size_t)d * CTX + s) = o;
                }
            }
          });
}

// S[b][i][j] = (q.k)/32, lower-triangular 256x256 tiles (36 per batch)
__global__ __launch_bounds__(512, 4) void k_score(const u16* __restrict__ qkb,
                                                  float* __restrict__ S) {
  const int u = (blockIdx.x & 7) * 36 + (blockIdx.x >> 3);  // 288%8==0
  const int b = u / 36, v = u % 36;
  int it = 0;
  while ((it + 1) * (it + 2) / 2 <= v) ++it;
  const int jt = v - it * (it + 1) / 2;
  const u16* Aq = qkb + (size_t)b * CTX * 2048;
  float* C = S + ((size_t)b << 22);
  const int m0 = it * 256, n0 = jt * 256;
  gemm256(Aq, 2048, Aq + 1024, 2048, m0, n0, DOUT,
          [&](const f32x4(&acc)[8][4], int r0, int c0) {
#pragma unroll
            for (int fr = 0; fr < 8; ++fr)
#pragma unroll
              for (int nc = 0; nc < 4; ++nc) {
                const int r = m0 + r0 + fr * 16;
                const int c = n0 + c0 + nc * 16;
#pragma unroll
                for (int i = 0; i < 4; ++i)
                  C[(size_t)(r + i) * CTX + c] = acc[fr][nc][i] * 0.03125f;
              }
          });
}

// row softmax over S fp32, write P bf16 in place (row stride 4096 u16),
// full 2048 cols written (zeros above diagonal) so PV GEMM needs no masking.
__global__ __launch_bounds__(256) void k_softmax(float* __restrict__ Sws) {
  const int row = blockIdx.x;
  const int b = row >> 11, i = row & (CTX - 1);
  const float* srow = Sws + ((size_t)b << 22) + ((size_t)i << 11);
  u16* prow = (u16*)(Sws + ((size_t)b << 22)) + ((size_t)i << 12);
  const int t = threadIdx.x;
  const int j0 = t * 8;
  float vv[8];
  if (j0 <= i) {
    const float4 v0 = *reinterpret_cast<const float4*>(srow + j0);
    const float4 v1 = *reinterpret_cast<const float4*>(srow + j0 + 4);
    vv[0] = v0.x; vv[1] = v0.y; vv[2] = v0.z; vv[3] = v0.w;
    vv[4] = v1.x; vv[5] = v1.y; vv[6] = v1.z; vv[7] = v1.w;
  } else {
#pragma unroll
    for (int p = 0; p < 8; ++p) vv[p] = -3.0e38f;
  }
  float mx = -3.0e38f;
#pragma unroll
  for (int p = 0; p < 8; ++p) {
    vv[p] = (j0 + p <= i) ? vv[p] : -3.0e38f;
    mx = fmaxf(mx, vv[p]);
  }
#pragma unroll
  for (int off = 32; off > 0; off >>= 1) mx = fmaxf(mx, __shfl_xor(mx, off));
  __shared__ float redm[4], reds[4];
  const int lane = t & 63, wid = t >> 6;
  if (lane == 0) redm[wid] = mx;
  __syncthreads();
  mx = fmaxf(fmaxf(redm[0], redm[1]), fmaxf(redm[2], redm[3]));
  float e[8], s = 0.f;
#pragma unroll
  for (int p = 0; p < 8; ++p) {
    e[p] = __expf(vv[p] - mx);
    s += e[p];
  }
#pragma unroll
  for (int off = 32; off > 0; off >>= 1) s += __shfl_xor(s, off);
  if (lane == 0) reds[wid] = s;
  __syncthreads();  // orders row reads above before in-place writes below
  s = reds[0] + reds[1] + reds[2] + reds[3];
  const float inv = 1.0f / s;
  ushort4 o0, o1;
  o0.x = (j0 + 0 <= i) ? f2bf(e[0] * inv) : (u16)0;
  o0.y = (j0 + 1 <= i) ? f2bf(e[1] * inv) : (u16)0;
  o0.z = (j0 + 2 <= i) ? f2bf(e[2] * inv) : (u16)0;
  o0.w = (j0 + 3 <= i) ? f2bf(e[3] * inv) : (u16)0;
  o1.x = (j0 + 4 <= i) ? f2bf(e[4] * inv) : (u16)0;
  o1.y = (j0 + 5 <= i) ? f2bf(e[5] * inv) : (u16)0;
  o1.z = (j0 + 6 <= i) ? f2bf(e[6] * inv) : (u16)0;
  o1.w = (j0 + 7 <= i) ? f2bf(e[7] * inv) : (u16)0;
  *reinterpret_cast<ushort4*>(prow + j0) = o0;
  *reinterpret_cast<ushort4*>(prow + j0 + 4) = o1;
}

// out[b][i][d] = sum_j P[b][i][j] * V[b][j][d]; K causally limited; LPT order.
__global__ __launch_bounds__(512, 4) void k_out(const float* __restrict__ Sws,
                                                const u16* __restrict__ vT,
                                                float* __restrict__ out) {
  const int idx = blockIdx.x;          // 256 blocks = 8it x 8b x 4nt
  const int it = 7 - (idx >> 5);       // longest (K=2048) first
  const int b = (idx >> 2) & 7;
  const int nt = idx & 3;
  const u16* P = (const u16*)(Sws + ((size_t)b << 22));  // lda = 4096 u16
  const u16* Bt = vT + (size_t)b * DOUT * CTX;           // [D][S]
  float* C = out + (size_t)b * CTX * DOUT;
  const int m0 = it * 256, n0 = nt * 256;
  gemm256(P, 2 * CTX, Bt, CTX, m0, n0, (it + 1) * 256,
          [&](const f32x4(&acc)[8][4], int r0, int c0) {
#pragma unroll
            for (int fr = 0; fr < 8; ++fr)
#pragma unroll
              for (int nc = 0; nc < 4; ++nc) {
                const int r = m0 + r0 + fr * 16;
                const int c = n0 + c0 + nc * 16;
#pragma unroll
                for (int i = 0; i < 4; ++i)
                  C[(size_t)(r + i) * DOUT + c] = acc[fr][nc][i];
              }
          });
}

// ---------------------------------------------------------------------------
extern "C" void kernel_launch(void* const* d_in, const int* in_sizes, int n_in,
                              void* d_out, int out_size, void* d_ws, size_t ws_size,
                              hipStream_t stream) {
  (void)in_sizes; (void)n_in; (void)out_size; (void)ws_size;
  const float* x = (const float*)d_in[0];
  const float* Wq = (const float*)d_in[1];
  const float* Wk = (const float*)d_in[2];
  const float* Wv = (const float*)d_in[3];
  float* out = (float*)d_out;
  uint8_t* ws = (uint8_t*)d_ws;

  // ws layout (224 MB):
  //   [0,128M): S fp32 [8][2048][2048] (P bf16 written in place by softmax)
  //     xb bf16 (32MB) + Wt_all (6MB) overlap S -- dead before k_score runs
  //   [128M,192M): qkb bf16 [8][2048][2048] (q cols 0..1023, k cols 1024..2047)
  //   [192M,224M): vT bf16 [8][1024][2048]
  float* S = (float*)ws;
  u16* xb = (u16*)ws;
  u16* Wt_all = (u16*)(ws + 33554432ull);  // [3072][1024]: q|k|v
  u16* qkb = (u16*)(ws + 134217728ull);
  u16* vT = (u16*)(ws + 201326592ull);

  k_cvt_x<<<16384, 256, 0, stream>>>(x, xb);
  k_cvt_wt<<<256, 256, 0, stream>>>(Wq, Wt_all);
  k_cvt_wt<<<256, 256, 0, stream>>>(Wk, Wt_all + 1024ull * 1024);
  k_cvt_wt<<<256, 256, 0, stream>>>(Wv, Wt_all + 2048ull * 1024);
  k_proj<<<768, 512, 0, stream>>>(xb, Wt_all, qkb, vT);
  k_score<<<288, 512, 0, stream>>>(qkb, S);
  k_softmax<<<NB * CTX, 256, 0, stream>>>(S);
  k_out<<<256, 512, 0, stream>>>(S, vT, out);
}

// Round 11
// 351.914 us; speedup vs baseline: 6.1260x; 6.1260x over previous
//
#include <hip/hip_runtime.h>
#include <stdint.h>

typedef unsigned short u16;
typedef short bf16x8 __attribute__((ext_vector_type(8)));
typedef float f32x4 __attribute__((ext_vector_type(4)));

#define CTX 2048
#define DIN 1024
#define DOUT 1024
#define NB 8

__device__ __forceinline__ u16 f2bf(float f) {
  uint32_t u = __builtin_bit_cast(uint32_t, f);
  u += 0x7FFFu + ((u >> 16) & 1u);
  return (u16)(u >> 16);
}

// global -> LDS async, 16B per lane. LDS dest is wave-uniform base + lane*16.
__device__ __forceinline__ void gld_lds16(const u16* g, const u16* lds) {
  __builtin_amdgcn_global_load_lds(
      (const __attribute__((address_space(1))) uint32_t*)(unsigned long long)(const void*)g,
      (__attribute__((address_space(3))) uint32_t*)(uint32_t)(unsigned long long)(const void*)lds,
      16, 0, 0);
}

#define SBAR() asm volatile("s_barrier" ::: "memory")
#define VMCNT3() asm volatile("s_waitcnt vmcnt(3)" ::: "memory")
#define VMCNT0() asm volatile("s_waitcnt vmcnt(0)" ::: "memory")
#define SCHED0() __builtin_amdgcn_sched_barrier(0)

// ---------------------------------------------------------------------------
// 128x256-tile GEMM, bf16, BK=32, triple-buffered LDS (72 KB), 512 thr =
// 8 waves (2M x 4N); each wave owns a 64x64 quadrant = 4x4 frags (16x16x32).
// ROUND-11 KEY CHANGE: round 10's spill catastrophe (VGPR=64, 4 GB scratch)
// proved launch_bounds(512,4) caps the UNIFIED VGPR+AGPR budget at 128; the
// 256x256 tile needs ~240 (acc alone 128) -> infeasible; rounds 4-9 were 256
// combined -> hard 2 waves/SIMD -> 1 block/CU BY REGISTERS. This tile halves
// acc to 64; total ~115 <= 128 -> 2 blocks/CU genuinely co-resident
// (4 waves/SIMD). One block's MFMA bursts overlap the other block's DS/stage
// phases in hardware (m114 co-scheduling) -- the occupancy lever none of the
// six intra-block schedule variants could reach.
// LDS per buffer: A 128x32 (8KB) + B 256x32 (16KB) = 24KB; x3 = 72KB.
// Fragment order (16-row x 32-col blocks, lane-linear 16B): staging (linear
// DMA dest) and ds_read_b128 both conflict-free (measured 0 conflicts).
// Tile T reads buf[T%3]; body stages tile T+2 into buf[(T+2)%3] (never live).
// vmcnt ledger (3 gld_lds16 per staged tile; only VMEM in loop):
//   prologue: stage(0)+stage(1) = 6 in flight; vmcnt(3) -> stage(0) landed.
//   body T: stage(T+2) -> 6 in flight; vmcnt(3) retires stage(T+1), leaves
//   stage(T+2). When T+2>=nkt: only stage(T+1) in flight -> vmcnt(0).
// SCHED0 pins MFMAs + their lgkm waits above the vmcnt/barrier (rule 18).
// Accumulation order: ascending 32-k chunks (bitwise identical to r4-r10).
// Requires nkt >= 2 (call sites: nkt in {4..32}).
// ---------------------------------------------------------------------------
template <typename EPI>
__device__ __forceinline__ void gemm128x256(const u16* __restrict__ A, int lda,
                                            const u16* __restrict__ Bt, int ldb,
                                            int m0, int n0, int K, EPI&& epi) {
  __shared__ __align__(16) u16 lds[36864];  // 3 x [A 4096 | B 8192] u16 = 72 KB

  const int t = threadIdx.x;
  const int lane = t & 63;
  const int w = t >> 6;     // 0..7
  const int wm = w >> 2;    // 0..1 (m half: 64 rows)
  const int wn = w & 3;     // 0..3 (n quarter: 64 cols)
  const int l15 = lane & 15;
  const int l16 = lane >> 4;
  const int nkt = K >> 5;   // BK = 32

  f32x4 acc[4][4];
#pragma unroll
  for (int i = 0; i < 4; ++i)
#pragma unroll
    for (int j = 0; j < 4; ++j) acc[i][j] = {0.f, 0.f, 0.f, 0.f};

  // staging: wave w covers 16-row block w. A: 128 rows = 1 gld; B: 256 = 2.
  const u16* gA = A + (size_t)(m0 + w * 16 + l15) * lda + l16 * 8;
  const u16* gB = Bt + (size_t)(n0 + w * 16 + l15) * ldb + l16 * 8;
  const size_t ldJB = (size_t)128 * ldb;

  auto STAGE = [&](int kbuf, int T) {  // 3 gld_lds16: full 24KB tile T
    const size_t koff = (size_t)T * 32;
    u16* base = lds + kbuf * 12288;
    gld_lds16(gA + koff, base + w * 512);                 // A rows 0..127
    gld_lds16(gB + koff, base + 4096 + w * 512);          // B rows 0..127
    gld_lds16(gB + koff + ldJB, base + 8192 + w * 512);   // B rows 128..255
  };

  // prologue: tiles 0 and 1 in flight; tile 0 landed before first reads
  STAGE(0, 0);
  STAGE(1, 1);
  VMCNT3();
  SBAR();

  int cb = 0;  // T % 3
  int sb = 2;  // (T+2) % 3
  for (int T = 0; T < nkt; ++T) {
    if (T + 2 < nkt) STAGE(sb, T + 2);

    const u16* bufA = lds + cb * 12288 + (wm * 4) * 512 + lane * 8;
    const u16* bufB = lds + cb * 12288 + 4096 + (wn * 4) * 512 + lane * 8;
    bf16x8 ar[4], br[4];
#pragma unroll
    for (int fr = 0; fr < 4; ++fr)
      ar[fr] = *reinterpret_cast<const bf16x8*>(bufA + fr * 512);
#pragma unroll
    for (int nc = 0; nc < 4; ++nc)
      br[nc] = *reinterpret_cast<const bf16x8*>(bufB + nc * 512);

    __builtin_amdgcn_s_setprio(1);
#pragma unroll
    for (int fr = 0; fr < 4; ++fr)
#pragma unroll
      for (int nc = 0; nc < 4; ++nc)
        acc[fr][nc] = __builtin_amdgcn_mfma_f32_16x16x32_bf16(ar[fr], br[nc],
                                                              acc[fr][nc], 0, 0, 0);
    __builtin_amdgcn_s_setprio(0);
    SCHED0();  // pin MFMAs + their lgkm waits above the vmcnt/barrier (rule 18)
    if (T + 2 < nkt) {
      VMCNT3();  // retires stage(T+1), leaves stage(T+2)
    } else {
      VMCNT0();  // tail: only stage(T+1) (tile-old) in flight
    }
    SBAR();
    cb = (cb == 2) ? 0 : cb + 1;
    sb = (sb == 2) ? 0 : sb + 1;
  }

  // epilogue: row = r0 + fr*16 + i, col = c0 + nc*16 (tile-local)
  epi(acc, wm * 64 + l16 * 4, wn * 64 + l15);
}

// ---------------------------------------------------------------------------
__global__ __launch_bounds__(256) void k_cvt_x(const float* __restrict__ x,
                                               u16* __restrict__ xb) {
  const int idx = (blockIdx.x * 256 + threadIdx.x) * 4;
  const float4 v = *reinterpret_cast<const float4*>(x + idx);
  ushort4 o;
  o.x = f2bf(v.x); o.y = f2bf(v.y); o.z = f2bf(v.z); o.w = f2bf(v.w);
  *reinterpret_cast<ushort4*>(xb + idx) = o;
}

// W [DIN][DOUT] fp32 -> Wt [DOUT][DIN] bf16 (tiled transpose via LDS)
__global__ __launch_bounds__(256) void k_cvt_wt(const float* __restrict__ W,
                                                u16* __restrict__ Wt) {
  __shared__ u16 tile[64][65];
  const int bc = blockIdx.x;
  const int tr0 = (bc >> 4) * 64;
  const int tc0 = (bc & 15) * 64;
  const int t = threadIdx.x;
  const int col = t & 63, rr = t >> 6;
#pragma unroll
  for (int p = 0; p < 16; ++p) {
    const int row = rr * 16 + p;
    tile[row][col] = f2bf(W[(size_t)(tr0 + row) * DOUT + tc0 + col]);
  }
  __syncthreads();
#pragma unroll
  for (int p = 0; p < 16; ++p) {
    const int row = rr * 16 + p;
    Wt[(size_t)(tc0 + row) * DIN + tr0 + col] = tile[col][row];
  }
}

// Fused QKV projection. 1536 blocks (128 m x 12 n), XCD-swizzled.
// n-tiles 0-7 -> qk row-major, 8-11 -> vT transposed.
__global__ __launch_bounds__(512, 4) void k_proj(const u16* __restrict__ xb,
                                                 const u16* __restrict__ Wt,
                                                 u16* __restrict__ qkb,
                                                 u16* __restrict__ vT) {
  const int wg = (blockIdx.x & 7) * 192 + (blockIdx.x >> 3);  // bijective
  const int m0 = (wg / 12) * 128, n0 = (wg % 12) * 256;
  gemm128x256(xb, DIN, Wt, DIN, m0, n0, DIN,
              [&](const f32x4(&acc)[4][4], int r0, int c0) {
                if (n0 < 2 * DOUT) {  // q or k -> qkb row-major [16384][2048]
#pragma unroll
                  for (int fr = 0; fr < 4; ++fr)
#pragma unroll
                    for (int nc = 0; nc < 4; ++nc) {
                      const int r = m0 + r0 + fr * 16;
                      const int c = n0 + c0 + nc * 16;
#pragma unroll
                      for (int i = 0; i < 4; ++i)
                        qkb[(size_t)(r + i) * 2048 + c] = f2bf(acc[fr][nc][i]);
                    }
                } else {  // v -> vT[b][d][s]
                  const int b = m0 >> 11;
                  const int sl = (m0 & (CTX - 1)) + r0;
                  u16* C = vT + (size_t)b * DOUT * CTX;
#pragma unroll
                  for (int fr = 0; fr < 4; ++fr)
#pragma unroll
                    for (int nc = 0; nc < 4; ++nc) {
                      const int d = n0 - 2 * DOUT + c0 + nc * 16;
                      const int s = sl + fr * 16;
                      ushort4 o;
                      o.x = f2bf(acc[fr][nc][0]);
                      o.y = f2bf(acc[fr][nc][1]);
                      o.z = f2bf(acc[fr][nc][2]);
                      o.w = f2bf(acc[fr][nc][3]);
                      *reinterpret_cast<ushort4*>(C + (size_t)d * CTX + s) = o;
                    }
                }
              });
}

// S[b][i][j] = (q.k)/32, causal 128x256 tiles: it 0..15, jt 0..it/2
// (72 tiles per batch; diagonal-spanning tiles compute garbage above the
// diagonal -- softmax never reads it).
__global__ __launch_bounds__(512, 4) void k_score(const u16* __restrict__ qkb,
                                                  float* __restrict__ S) {
  const int u = (blockIdx.x & 7) * 72 + (blockIdx.x >> 3);  // 576%8==0
  const int b = u / 72, v = u % 72;
  int it = 0, pre = 0;
  while (pre + (it / 2 + 1) <= v) { pre += it / 2 + 1; ++it; }
  const int jt = v - pre;
  const u16* Aq = qkb + (size_t)b * CTX * 2048;
  float* C = S + ((size_t)b << 22);
  const int m0 = it * 128, n0 = jt * 256;
  gemm128x256(Aq, 2048, Aq + 1024, 2048, m0, n0, DOUT,
              [&](const f32x4(&acc)[4][4], int r0, int c0) {
#pragma unroll
                for (int fr = 0; fr < 4; ++fr)
#pragma unroll
                  for (int nc = 0; nc < 4; ++nc) {
                    const int r = m0 + r0 + fr * 16;
                    const int c = n0 + c0 + nc * 16;
#pragma unroll
                    for (int i = 0; i < 4; ++i)
                      C[(size_t)(r + i) * CTX + c] = acc[fr][nc][i] * 0.03125f;
                  }
              });
}

// row softmax over S fp32, write P bf16 in place (row stride 4096 u16),
// full 2048 cols written (zeros above diagonal) so PV GEMM needs no masking.
__global__ __launch_bounds__(256) void k_softmax(float* __restrict__ Sws) {
  const int row = blockIdx.x;
  const int b = row >> 11, i = row & (CTX - 1);
  const float* srow = Sws + ((size_t)b << 22) + ((size_t)i << 11);
  u16* prow = (u16*)(Sws + ((size_t)b << 22)) + ((size_t)i << 12);
  const int t = threadIdx.x;
  const int j0 = t * 8;
  float vv[8];
  if (j0 <= i) {
    const float4 v0 = *reinterpret_cast<const float4*>(srow + j0);
    const float4 v1 = *reinterpret_cast<const float4*>(srow + j0 + 4);
    vv[0] = v0.x; vv[1] = v0.y; vv[2] = v0.z; vv[3] = v0.w;
    vv[4] = v1.x; vv[5] = v1.y; vv[6] = v1.z; vv[7] = v1.w;
  } else {
#pragma unroll
    for (int p = 0; p < 8; ++p) vv[p] = -3.0e38f;
  }
  float mx = -3.0e38f;
#pragma unroll
  for (int p = 0; p < 8; ++p) {
    vv[p] = (j0 + p <= i) ? vv[p] : -3.0e38f;
    mx = fmaxf(mx, vv[p]);
  }
#pragma unroll
  for (int off = 32; off > 0; off >>= 1) mx = fmaxf(mx, __shfl_xor(mx, off));
  __shared__ float redm[4], reds[4];
  const int lane = t & 63, wid = t >> 6;
  if (lane == 0) redm[wid] = mx;
  __syncthreads();
  mx = fmaxf(fmaxf(redm[0], redm[1]), fmaxf(redm[2], redm[3]));
  float e[8], s = 0.f;
#pragma unroll
  for (int p = 0; p < 8; ++p) {
    e[p] = __expf(vv[p] - mx);
    s += e[p];
  }
#pragma unroll
  for (int off = 32; off > 0; off >>= 1) s += __shfl_xor(s, off);
  if (lane == 0) reds[wid] = s;
  __syncthreads();  // orders row reads above before in-place writes below
  s = reds[0] + reds[1] + reds[2] + reds[3];
  const float inv = 1.0f / s;
  ushort4 o0, o1;
  o0.x = (j0 + 0 <= i) ? f2bf(e[0] * inv) : (u16)0;
  o0.y = (j0 + 1 <= i) ? f2bf(e[1] * inv) : (u16)0;
  o0.z = (j0 + 2 <= i) ? f2bf(e[2] * inv) : (u16)0;
  o0.w = (j0 + 3 <= i) ? f2bf(e[3] * inv) : (u16)0;
  o1.x = (j0 + 4 <= i) ? f2bf(e[4] * inv) : (u16)0;
  o1.y = (j0 + 5 <= i) ? f2bf(e[5] * inv) : (u16)0;
  o1.z = (j0 + 6 <= i) ? f2bf(e[6] * inv) : (u16)0;
  o1.w = (j0 + 7 <= i) ? f2bf(e[7] * inv) : (u16)0;
  *reinterpret_cast<ushort4*>(prow + j0) = o0;
  *reinterpret_cast<ushort4*>(prow + j0 + 4) = o1;
}

// out[b][i][d] = sum_j P[b][i][j] * V[b][j][d]; K causally limited; LPT order.
__global__ __launch_bounds__(512, 4) void k_out(const float* __restrict__ Sws,
                                                const u16* __restrict__ vT,
                                                float* __restrict__ out) {
  const int idx = blockIdx.x;          // 512 blocks = 16it x 8b x 4nt
  const int it = 15 - (idx >> 5);      // longest (K=2048) first
  const int b = (idx >> 2) & 7;
  const int nt = idx & 3;
  const u16* P = (const u16*)(Sws + ((size_t)b << 22));  // lda = 4096 u16
  const u16* Bt = vT + (size_t)b * DOUT * CTX;           // [D][S]
  float* C = out + (size_t)b * CTX * DOUT;
  const int m0 = it * 128, n0 = nt * 256;
  gemm128x256(P, 2 * CTX, Bt, CTX, m0, n0, (it + 1) * 128,
              [&](const f32x4(&acc)[4][4], int r0, int c0) {
#pragma unroll
                for (int fr = 0; fr < 4; ++fr)
#pragma unroll
                  for (int nc = 0; nc < 4; ++nc) {
                    const int r = m0 + r0 + fr * 16;
                    const int c = n0 + c0 + nc * 16;
#pragma unroll
                    for (int i = 0; i < 4; ++i)
                      C[(size_t)(r + i) * DOUT + c] = acc[fr][nc][i];
                  }
              });
}

// ---------------------------------------------------------------------------
extern "C" void kernel_launch(void* const* d_in, const int* in_sizes, int n_in,
                              void* d_out, int out_size, void* d_ws, size_t ws_size,
                              hipStream_t stream) {
  (void)in_sizes; (void)n_in; (void)out_size; (void)ws_size;
  const float* x = (const float*)d_in[0];
  const float* Wq = (const float*)d_in[1];
  const float* Wk = (const float*)d_in[2];
  const float* Wv = (const float*)d_in[3];
  float* out = (float*)d_out;
  uint8_t* ws = (uint8_t*)d_ws;

  // ws layout (224 MB):
  //   [0,128M): S fp32 [8][2048][2048] (P bf16 written in place by softmax)
  //     xb bf16 (32MB) + Wt_all (6MB) overlap S -- dead before k_score runs
  //   [128M,192M): qkb bf16 [8][2048][2048] (q cols 0..1023, k cols 1024..2047)
  //   [192M,224M): vT bf16 [8][1024][2048]
  float* S = (float*)ws;
  u16* xb = (u16*)ws;
  u16* Wt_all = (u16*)(ws + 33554432ull);  // [3072][1024]: q|k|v
  u16* qkb = (u16*)(ws + 134217728ull);
  u16* vT = (u16*)(ws + 201326592ull);

  k_cvt_x<<<16384, 256, 0, stream>>>(x, xb);
  k_cvt_wt<<<256, 256, 0, stream>>>(Wq, Wt_all);
  k_cvt_wt<<<256, 256, 0, stream>>>(Wk, Wt_all + 1024ull * 1024);
  k_cvt_wt<<<256, 256, 0, stream>>>(Wv, Wt_all + 2048ull * 1024);
  k_proj<<<1536, 512, 0, stream>>>(xb, Wt_all, qkb, vT);
  k_score<<<576, 512, 0, stream>>>(qkb, S);
  k_softmax<<<NB * CTX, 256, 0, stream>>>(S);
  k_out<<<512, 512, 0, stream>>>(S, vT, out);
}

// Round 12
// 323.084 us; speedup vs baseline: 6.6726x; 1.0892x over previous
//
#include <hip/hip_runtime.h>
#include <stdint.h>

typedef unsigned short u16;
typedef short bf16x8 __attribute__((ext_vector_type(8)));
typedef float f32x4 __attribute__((ext_vector_type(4)));

#define CTX 2048
#define DIN 1024
#define DOUT 1024
#define NB 8

__device__ __forceinline__ u16 f2bf(float f) {
  uint32_t u = __builtin_bit_cast(uint32_t, f);
  u += 0x7FFFu + ((u >> 16) & 1u);
  return (u16)(u >> 16);
}

// global -> LDS async, 16B per lane. LDS dest is wave-uniform base + lane*16.
__device__ __forceinline__ void gld_lds16(const u16* g, const u16* lds) {
  __builtin_amdgcn_global_load_lds(
      (const __attribute__((address_space(1))) uint32_t*)(unsigned long long)(const void*)g,
      (__attribute__((address_space(3))) uint32_t*)(uint32_t)(unsigned long long)(const void*)lds,
      16, 0, 0);
}

#define SBAR() asm volatile("s_barrier" ::: "memory")
#define VMCNT4() asm volatile("s_waitcnt vmcnt(4)" ::: "memory")
#define VMCNT0() asm volatile("s_waitcnt vmcnt(0)" ::: "memory")
#define LGKM0() asm volatile("s_waitcnt lgkmcnt(0)" ::: "memory")

// ---------------------------------------------------------------------------
// 256x256-tile GEMM, bf16, BK=32, 3 LDS buffers + REGISTER-BANKED operands.
// ROUND-12 KEY CHANGE: r6's 6674 cyc/K-tile-64 decomposes as MFMA 2064 + DS
// 2304 + staging 1170 + barriers + VALU -- fully SERIAL, because each tile's
// ds_reads feed the SAME tile's MFMAs (lgkm forces read-drain before matrix
// work) and both waves/SIMD are barrier phase-locked. Fix: double-bank the
// operand REGISTERS -- body T runs MFMA(tile T, from bank T&1) with no lgkm
// dependency while issuing ds_reads(tile T+1 -> bank (T+1)&1); DS drain hides
// under MFMA execution within the same wave.
// Pipeline (tile X lives in LDS buf[X%3]):
//   body T: {STAGE(T+3 -> buf[T%3]); ds_read(T+1 <- buf[(T+1)%3]) -> bank;
//            MFMA(T from bank); lgkmcnt(0); vmcnt(4)|0; s_barrier}
// Safety:
//  - STAGE(T+3) overwrites buf[T%3], whose tile-T reads happened in body T-1
//    and were drained by that body's lgkmcnt(0) before its barrier.
//  - reads(T+1) need stage(T+1) landed: retired by the counted vmcnt at the
//    end of body T-2 (stage is 3 bodies ahead, wait is on a 2-body-old DMA
//    -> never a fresh-latency stall; steady state NEVER drains to 0).
//  - vmcnt ledger (4 gld_lds16/stage): prologue stages 0,1,2 (12 in flight),
//    vmcnt(4) retires 0,1, leaves 2. End of body T: outstanding =
//    stage(T+2)[old] + stage(T+3)[this body] = 8 -> vmcnt(4) retires
//    stage(T+2) (read next body), leaves stage(T+3). When T+3>=nkt: vmcnt(0)
//    (waits only tile-old stages) [r3 race class excluded by induction].
//  - banks statically indexed via unrolled pair-loop (rule 20; nkt even).
// Regs: acc 128 + banks 96 + addr ~20 = ~245 <= 256 -> 2 waves/SIMD (as
// before); the overlap is now intra-wave, not occupancy-dependent.
// Requires nkt >= 4 and even (call sites: 8..64, 32).
// ---------------------------------------------------------------------------
template <typename EPI>
__device__ __forceinline__ void gemm256(const u16* __restrict__ A, int lda,
                                        const u16* __restrict__ Bt, int ldb,
                                        int m0, int n0, int K, EPI&& epi) {
  __shared__ __align__(16) u16 lds[49152];  // 3 bufs x (A 8192 | B 8192) u16

  const int t = threadIdx.x;
  const int lane = t & 63;
  const int w = t >> 6;     // 0..7
  const int wm = w >> 2;    // 0..1 (m half)
  const int wn = w & 3;     // 0..3 (n col group)
  const int l15 = lane & 15;
  const int l16 = lane >> 4;
  const int nkt = K >> 5;   // BK = 32

  f32x4 acc[8][4];
#pragma unroll
  for (int i = 0; i < 8; ++i)
#pragma unroll
    for (int j = 0; j < 4; ++j) acc[i][j] = {0.f, 0.f, 0.f, 0.f};

  const u16* gA = A + (size_t)(m0 + w * 16 + l15) * lda + l16 * 8;
  const u16* gB = Bt + (size_t)(n0 + w * 16 + l15) * ldb + l16 * 8;
  const size_t ldJA = (size_t)128 * lda;
  const size_t ldJB = (size_t)128 * ldb;

  auto STAGE = [&](int kbuf, int T) {  // 4 gld_lds16: full 32KB tile T
    const size_t koff = (size_t)T * 32;
    u16* base = lds + kbuf * 16384;
    gld_lds16(gA + koff, base + w * 512);                  // A rows 0..127
    gld_lds16(gA + koff + ldJA, base + 4096 + w * 512);    // A rows 128..255
    gld_lds16(gB + koff, base + 8192 + w * 512);           // B rows 0..127
    gld_lds16(gB + koff + ldJB, base + 12288 + w * 512);   // B rows 128..255
  };

  bf16x8 a0[8], b0[4], a1[8], b1[4];

  auto READT = [&](int kbuf, bf16x8(&ar)[8], bf16x8(&br)[4]) {
    const u16* bufA = lds + kbuf * 16384 + (wm * 8) * 512 + lane * 8;
    const u16* bufB = lds + kbuf * 16384 + 8192 + (wn * 4) * 512 + lane * 8;
#pragma unroll
    for (int fr = 0; fr < 8; ++fr)
      ar[fr] = *reinterpret_cast<const bf16x8*>(bufA + fr * 512);
#pragma unroll
    for (int nc = 0; nc < 4; ++nc)
      br[nc] = *reinterpret_cast<const bf16x8*>(bufB + nc * 512);
  };

  auto MMA = [&](bf16x8(&ar)[8], bf16x8(&br)[4]) {
    __builtin_amdgcn_s_setprio(1);
#pragma unroll
    for (int fr = 0; fr < 8; ++fr)
#pragma unroll
      for (int nc = 0; nc < 4; ++nc)
        acc[fr][nc] = __builtin_amdgcn_mfma_f32_16x16x32_bf16(ar[fr], br[nc],
                                                              acc[fr][nc], 0, 0, 0);
    __builtin_amdgcn_s_setprio(0);
  };

  // prologue: stage tiles 0,1,2; land 0,1 (keep 2 in flight); read tile 0.
  STAGE(0, 0);
  STAGE(1, 1);
  STAGE(2, 2);
  VMCNT4();  // retires stages 0,1 (8 oldest); stage 2 stays in flight
  SBAR();
  READT(0, a0, b0);
  LGKM0();   // tile-0 reads drained before body0 overwrites buf0
  SBAR();

  // buffer indices for the pair (T, T+1): cS0 = T%3, cS1 = (T+1)%3,
  // cR1 = (T+1)%3 (== cS1), cR2 = (T+2)%3.
  int c0 = 0, c1 = 1, c2 = 2;
  for (int T = 0; T < nkt; T += 2) {
    // ---- even body: MFMA tile T (bank0); read tile T+1 -> bank1
    if (T + 3 < nkt) STAGE(c0, T + 3);
    if (T + 1 < nkt) READT(c1, a1, b1);
    MMA(a0, b0);
    LGKM0();
    if (T + 3 < nkt) { VMCNT4(); } else { VMCNT0(); }
    SBAR();

    // ---- odd body: MFMA tile T+1 (bank1); read tile T+2 -> bank0
    if (T + 4 < nkt) STAGE(c1, T + 4);
    if (T + 2 < nkt) READT(c2, a0, b0);
    MMA(a1, b1);
    LGKM0();
    if (T + 4 < nkt) { VMCNT4(); } else { VMCNT0(); }
    SBAR();

    // advance pair: (c0,c1,c2) <- ((T+2)%3, (T+3)%3, (T+4)%3)
    const int n0_ = c2, n1_ = c0, n2_ = c1;
    c0 = n0_; c1 = n1_; c2 = n2_;
  }

  // epilogue: row = r0 + fr*16 + i, col = c0 + nc*16 (tile-local)
  epi(acc, wm * 128 + l16 * 4, wn * 64 + l15);
}

// ---------------------------------------------------------------------------
__global__ __launch_bounds__(256) void k_cvt_x(const float* __restrict__ x,
                                               u16* __restrict__ xb) {
  const int idx = (blockIdx.x * 256 + threadIdx.x) * 4;
  const float4 v = *reinterpret_cast<const float4*>(x + idx);
  ushort4 o;
  o.x = f2bf(v.x); o.y = f2bf(v.y); o.z = f2bf(v.z); o.w = f2bf(v.w);
  *reinterpret_cast<ushort4*>(xb + idx) = o;
}

// W [DIN][DOUT] fp32 -> Wt [DOUT][DIN] bf16 (tiled transpose via LDS)
__global__ __launch_bounds__(256) void k_cvt_wt(const float* __restrict__ W,
                                                u16* __restrict__ Wt) {
  __shared__ u16 tile[64][65];
  const int bc = blockIdx.x;
  const int tr0 = (bc >> 4) * 64;
  const int tc0 = (bc & 15) * 64;
  const int t = threadIdx.x;
  const int col = t & 63, rr = t >> 6;
#pragma unroll
  for (int p = 0; p < 16; ++p) {
    const int row = rr * 16 + p;
    tile[row][col] = f2bf(W[(size_t)(tr0 + row) * DOUT + tc0 + col]);
  }
  __syncthreads();
#pragma unroll
  for (int p = 0; p < 16; ++p) {
    const int row = rr * 16 + p;
    Wt[(size_t)(tc0 + row) * DIN + tr0 + col] = tile[col][row];
  }
}

// Fused QKV projection. 768 blocks, XCD-swizzled; n-tiles 0-7 -> qk row-major,
// 8-11 -> vT transposed.
__global__ __launch_bounds__(512, 2) void k_proj(const u16* __restrict__ xb,
                                                 const u16* __restrict__ Wt,
                                                 u16* __restrict__ qkb,
                                                 u16* __restrict__ vT) {
  const int wg = (blockIdx.x & 7) * 96 + (blockIdx.x >> 3);  // bijective, 768%8==0
  const int m0 = (wg / 12) * 256, n0 = (wg % 12) * 256;
  gemm256(xb, DIN, Wt, DIN, m0, n0, DIN,
          [&](const f32x4(&acc)[8][4], int r0, int c0) {
            if (n0 < 2 * DOUT) {  // q or k -> qkb row-major [16384][2048]
#pragma unroll
              for (int fr = 0; fr < 8; ++fr)
#pragma unroll
                for (int nc = 0; nc < 4; ++nc) {
                  const int r = m0 + r0 + fr * 16;
                  const int c = n0 + c0 + nc * 16;
#pragma unroll
                  for (int i = 0; i < 4; ++i)
                    qkb[(size_t)(r + i) * 2048 + c] = f2bf(acc[fr][nc][i]);
                }
            } else {  // v -> vT[b][d][s]
              const int b = m0 >> 11;
              const int sl = (m0 & (CTX - 1)) + r0;
              u16* C = vT + (size_t)b * DOUT * CTX;
#pragma unroll
              for (int fr = 0; fr < 8; ++fr)
#pragma unroll
                for (int nc = 0; nc < 4; ++nc) {
                  const int d = n0 - 2 * DOUT + c0 + nc * 16;
                  const int s = sl + fr * 16;
                  ushort4 o;
                  o.x = f2bf(acc[fr][nc][0]);
                  o.y = f2bf(acc[fr][nc][1]);
                  o.z = f2bf(acc[fr][nc][2]);
                  o.w = f2bf(acc[fr][nc][3]);
                  *reinterpret_cast<ushort4*>(C + (size_t)d * CTX + s) = o;
                }
            }
          });
}

// S[b][i][j] = (q.k)/32, lower-triangular 256x256 tiles (36 per batch)
__global__ __launch_bounds__(512, 2) void k_score(const u16* __restrict__ qkb,
                                                  float* __restrict__ S) {
  const int u = (blockIdx.x & 7) * 36 + (blockIdx.x >> 3);  // 288%8==0
  const int b = u / 36, v = u % 36;
  int it = 0;
  while ((it + 1) * (it + 2) / 2 <= v) ++it;
  const int jt = v - it * (it + 1) / 2;
  const u16* Aq = qkb + (size_t)b * CTX * 2048;
  float* C = S + ((size_t)b << 22);
  const int m0 = it * 256, n0 = jt * 256;
  gemm256(Aq, 2048, Aq + 1024, 2048, m0, n0, DOUT,
          [&](const f32x4(&acc)[8][4], int r0, int c0) {
#pragma unroll
            for (int fr = 0; fr < 8; ++fr)
#pragma unroll
              for (int nc = 0; nc < 4; ++nc) {
                const int r = m0 + r0 + fr * 16;
                const int c = n0 + c0 + nc * 16;
#pragma unroll
                for (int i = 0; i < 4; ++i)
                  C[(size_t)(r + i) * CTX + c] = acc[fr][nc][i] * 0.03125f;
              }
          });
}

// row softmax over S fp32, write P bf16 in place (row stride 4096 u16),
// full 2048 cols written (zeros above diagonal) so PV GEMM needs no masking.
__global__ __launch_bounds__(256) void k_softmax(float* __restrict__ Sws) {
  const int row = blockIdx.x;
  const int b = row >> 11, i = row & (CTX - 1);
  const float* srow = Sws + ((size_t)b << 22) + ((size_t)i << 11);
  u16* prow = (u16*)(Sws + ((size_t)b << 22)) + ((size_t)i << 12);
  const int t = threadIdx.x;
  const int j0 = t * 8;
  float vv[8];
  if (j0 <= i) {
    const float4 v0 = *reinterpret_cast<const float4*>(srow + j0);
    const float4 v1 = *reinterpret_cast<const float4*>(srow + j0 + 4);
    vv[0] = v0.x; vv[1] = v0.y; vv[2] = v0.z; vv[3] = v0.w;
    vv[4] = v1.x; vv[5] = v1.y; vv[6] = v1.z; vv[7] = v1.w;
  } else {
#pragma unroll
    for (int p = 0; p < 8; ++p) vv[p] = -3.0e38f;
  }
  float mx = -3.0e38f;
#pragma unroll
  for (int p = 0; p < 8; ++p) {
    vv[p] = (j0 + p <= i) ? vv[p] : -3.0e38f;
    mx = fmaxf(mx, vv[p]);
  }
#pragma unroll
  for (int off = 32; off > 0; off >>= 1) mx = fmaxf(mx, __shfl_xor(mx, off));
  __shared__ float redm[4], reds[4];
  const int lane = t & 63, wid = t >> 6;
  if (lane == 0) redm[wid] = mx;
  __syncthreads();
  mx = fmaxf(fmaxf(redm[0], redm[1]), fmaxf(redm[2], redm[3]));
  float e[8], s = 0.f;
#pragma unroll
  for (int p = 0; p < 8; ++p) {
    e[p] = __expf(vv[p] - mx);
    s += e[p];
  }
#pragma unroll
  for (int off = 32; off > 0; off >>= 1) s += __shfl_xor(s, off);
  if (lane == 0) reds[wid] = s;
  __syncthreads();  // orders row reads above before in-place writes below
  s = reds[0] + reds[1] + reds[2] + reds[3];
  const float inv = 1.0f / s;
  ushort4 o0, o1;
  o0.x = (j0 + 0 <= i) ? f2bf(e[0] * inv) : (u16)0;
  o0.y = (j0 + 1 <= i) ? f2bf(e[1] * inv) : (u16)0;
  o0.z = (j0 + 2 <= i) ? f2bf(e[2] * inv) : (u16)0;
  o0.w = (j0 + 3 <= i) ? f2bf(e[3] * inv) : (u16)0;
  o1.x = (j0 + 4 <= i) ? f2bf(e[4] * inv) : (u16)0;
  o1.y = (j0 + 5 <= i) ? f2bf(e[5] * inv) : (u16)0;
  o1.z = (j0 + 6 <= i) ? f2bf(e[6] * inv) : (u16)0;
  o1.w = (j0 + 7 <= i) ? f2bf(e[7] * inv) : (u16)0;
  *reinterpret_cast<ushort4*>(prow + j0) = o0;
  *reinterpret_cast<ushort4*>(prow + j0 + 4) = o1;
}

// out[b][i][d] = sum_j P[b][i][j] * V[b][j][d]; K causally limited; LPT order.
__global__ __launch_bounds__(512, 2) void k_out(const float* __restrict__ Sws,
                                                const u16* __restrict__ vT,
                                                float* __restrict__ out) {
  const int idx = blockIdx.x;          // 256 blocks = 8it x 8b x 4nt
  const int it = 7 - (idx >> 5);       // longest (K=2048) first
  const int b = (idx >> 2) & 7;
  const int nt = idx & 3;
  const u16* P = (const u16*)(Sws + ((size_t)b << 22));  // lda = 4096 u16
  const u16* Bt = vT + (size_t)b * DOUT * CTX;           // [D][S]
  float* C = out + (size_t)b * CTX * DOUT;
  const int m0 = it * 256, n0 = nt * 256;
  gemm256(P, 2 * CTX, Bt, CTX, m0, n0, (it + 1) * 256,
          [&](const f32x4(&acc)[8][4], int r0, int c0) {
#pragma unroll
            for (int fr = 0; fr < 8; ++fr)
#pragma unroll
              for (int nc = 0; nc < 4; ++nc) {
                const int r = m0 + r0 + fr * 16;
                const int c = n0 + c0 + nc * 16;
#pragma unroll
                for (int i = 0; i < 4; ++i)
                  C[(size_t)(r + i) * DOUT + c] = acc[fr][nc][i];
              }
          });
}

// ---------------------------------------------------------------------------
extern "C" void kernel_launch(void* const* d_in, const int* in_sizes, int n_in,
                              void* d_out, int out_size, void* d_ws, size_t ws_size,
                              hipStream_t stream) {
  (void)in_sizes; (void)n_in; (void)out_size; (void)ws_size;
  const float* x = (const float*)d_in[0];
  const float* Wq = (const float*)d_in[1];
  const float* Wk = (const float*)d_in[2];
  const float* Wv = (const float*)d_in[3];
  float* out = (float*)d_out;
  uint8_t* ws = (uint8_t*)d_ws;

  // ws layout (224 MB):
  //   [0,128M): S fp32 [8][2048][2048] (P bf16 written in place by softmax)
  //     xb bf16 (32MB) + Wt_all (6MB) overlap S -- dead before k_score runs
  //   [128M,192M): qkb bf16 [8][2048][2048] (q cols 0..1023, k cols 1024..2047)
  //   [192M,224M): vT bf16 [8][1024][2048]
  float* S = (float*)ws;
  u16* xb = (u16*)ws;
  u16* Wt_all = (u16*)(ws + 33554432ull);  // [3072][1024]: q|k|v
  u16* qkb = (u16*)(ws + 134217728ull);
  u16* vT = (u16*)(ws + 201326592ull);

  k_cvt_x<<<16384, 256, 0, stream>>>(x, xb);
  k_cvt_wt<<<256, 256, 0, stream>>>(Wq, Wt_all);
  k_cvt_wt<<<256, 256, 0, stream>>>(Wk, Wt_all + 1024ull * 1024);
  k_cvt_wt<<<256, 256, 0, stream>>>(Wv, Wt_all + 2048ull * 1024);
  k_proj<<<768, 512, 0, stream>>>(xb, Wt_all, qkb, vT);
  k_score<<<288, 512, 0, stream>>>(qkb, S);
  k_softmax<<<NB * CTX, 256, 0, stream>>>(S);
  k_out<<<256, 512, 0, stream>>>(S, vT, out);
}

// Round 14
// 294.574 us; speedup vs baseline: 7.3184x; 1.0968x over previous
//
#include <hip/hip_runtime.h>
#include <stdint.h>

typedef unsigned short u16;
typedef short bf16x8 __attribute__((ext_vector_type(8)));
typedef float f32x4 __attribute__((ext_vector_type(4)));

#define CTX 2048
#define DIN 1024
#define DOUT 1024
#define NB 8

__device__ __forceinline__ u16 f2bf(float f) {
  uint32_t u = __builtin_bit_cast(uint32_t, f);
  u += 0x7FFFu + ((u >> 16) & 1u);
  return (u16)(u >> 16);
}

// global -> LDS async, 16B per lane. LDS dest is wave-uniform base + lane*16.
__device__ __forceinline__ void gld_lds16(const u16* g, const u16* lds) {
  __builtin_amdgcn_global_load_lds(
      (const __attribute__((address_space(1))) uint32_t*)(unsigned long long)(const void*)g,
      (__attribute__((address_space(3))) uint32_t*)(uint32_t)(unsigned long long)(const void*)lds,
      16, 0, 0);
}

#define SBAR() asm volatile("s_barrier" ::: "memory")
#define VMCNT4() asm volatile("s_waitcnt vmcnt(4)" ::: "memory")
#define VMCNT3() asm volatile("s_waitcnt vmcnt(3)" ::: "memory")
#define VMCNT0() asm volatile("s_waitcnt vmcnt(0)" ::: "memory")

// ---------------------------------------------------------------------------
// 256x256-tile GEMM core -- r6 version verbatim (best measured total).
// Rotated schedule, 4 barriers/K-tile, K-loop unrolled x2. vmcnt ledger
// verified r4/r6. Requires nkt even >= 4 (call sites: 32). Single call per
// kernel (no vmcnt follows the epilogue stores -> store/load retirement
// ordering never matters here).
// ---------------------------------------------------------------------------
template <typename EPI>
__device__ __forceinline__ void gemm256(const u16* __restrict__ A, int lda,
                                        const u16* __restrict__ Bt, int ldb,
                                        int m0, int n0, int K, EPI&& epi) {
  __shared__ __align__(16) u16 lds[65536];  // [buf2][region4][block16][512]

  const int t = threadIdx.x;
  const int lane = t & 63;
  const int w = t >> 6;
  const int wm = w >> 2;
  const int wn = w & 3;
  const int l15 = lane & 15;
  const int l16 = lane >> 4;
  const int nkt = K >> 6;
  const int bf0 = (wn & 1) * 4;

  f32x4 acc[8][4];
#pragma unroll
  for (int i = 0; i < 8; ++i)
#pragma unroll
    for (int j = 0; j < 4; ++j) acc[i][j] = {0.f, 0.f, 0.f, 0.f};

  const u16* gA0 = A + (size_t)(m0 + w * 16 + l15) * lda + l16 * 8;
  const u16* gA1 = gA0 + (size_t)128 * lda;
  const u16* gB0 = Bt + (size_t)(n0 + w * 16 + l15) * ldb + l16 * 8;
  const u16* gB1 = gB0 + (size_t)128 * ldb;

  auto STAGEH = [&](int bb, int rr, const u16* g) {
    u16* d = lds + (((bb * 4 + rr) * 16) + w * 2) * 512;
    gld_lds16(g, d);
    gld_lds16(g + 32, d + 512);
  };

  STAGEH(0, 0, gA0);
  STAGEH(0, 1, gA1);
  STAGEH(0, 2, gB0);
  STAGEH(0, 3, gB1);
  if (nkt > 1) {
    STAGEH(1, 0, gA0 + 64);
    STAGEH(1, 1, gA1 + 64);
  }
  VMCNT4();
  SBAR();

  bf16x8 arLo[4][2], arHi[4][2], br[2][2];

  {
    if (1 < nkt) STAGEH(1, 2, gB0 + 64);
    const u16* bufA = lds + ((0 * 4 + wm) * 16) * 512 + lane * 8;
    const u16* bufB = lds + ((0 * 4 + 2 + (wn >> 1)) * 16) * 512 + lane * 8;
#pragma unroll
    for (int fr = 0; fr < 4; ++fr)
#pragma unroll
      for (int ks = 0; ks < 2; ++ks)
        arLo[fr][ks] = *reinterpret_cast<const bf16x8*>(bufA + (fr * 2 + ks) * 512);
#pragma unroll
    for (int nc = 0; nc < 2; ++nc)
#pragma unroll
      for (int ks = 0; ks < 2; ++ks)
        br[nc][ks] = *reinterpret_cast<const bf16x8*>(bufB + ((bf0 + nc) * 2 + ks) * 512);
    SBAR();
  }

  auto kbody = [&](int T, int b) {
    const u16* bufA = lds + ((b * 4 + wm) * 16) * 512 + lane * 8;
    const u16* bufB = lds + ((b * 4 + 2 + (wn >> 1)) * 16) * 512 + lane * 8;
    const u16* bufAn = lds + (((b ^ 1) * 4 + wm) * 16) * 512 + lane * 8;
    const u16* bufBn = lds + (((b ^ 1) * 4 + 2 + (wn >> 1)) * 16) * 512 + lane * 8;

    if (T + 1 < nkt) STAGEH(b ^ 1, 3, gB1 + (size_t)(T + 1) * 64);
    __builtin_amdgcn_s_setprio(1);
#pragma unroll
    for (int fr = 0; fr < 4; ++fr)
#pragma unroll
      for (int nc = 0; nc < 2; ++nc)
#pragma unroll
        for (int ks = 0; ks < 2; ++ks)
          acc[fr][nc] = __builtin_amdgcn_mfma_f32_16x16x32_bf16(arLo[fr][ks], br[nc][ks],
                                                                acc[fr][nc], 0, 0, 0);
    __builtin_amdgcn_s_setprio(0);
#pragma unroll
    for (int fr = 0; fr < 4; ++fr)
#pragma unroll
      for (int ks = 0; ks < 2; ++ks)
        arHi[fr][ks] = *reinterpret_cast<const bf16x8*>(bufA + ((fr + 4) * 2 + ks) * 512);
    SBAR();

    if (T + 2 < nkt) STAGEH(b, 0, gA0 + (size_t)(T + 2) * 64);
    __builtin_amdgcn_s_setprio(1);
#pragma unroll
    for (int fr = 0; fr < 4; ++fr)
#pragma unroll
      for (int nc = 0; nc < 2; ++nc)
#pragma unroll
        for (int ks = 0; ks < 2; ++ks)
          acc[4 + fr][nc] = __builtin_amdgcn_mfma_f32_16x16x32_bf16(arHi[fr][ks], br[nc][ks],
                                                                    acc[4 + fr][nc], 0, 0, 0);
    __builtin_amdgcn_s_setprio(0);
#pragma unroll
    for (int nc = 0; nc < 2; ++nc)
#pragma unroll
      for (int ks = 0; ks < 2; ++ks)
        br[nc][ks] = *reinterpret_cast<const bf16x8*>(bufB + ((bf0 + 2 + nc) * 2 + ks) * 512);
    SBAR();

    if (T + 2 < nkt) STAGEH(b, 1, gA1 + (size_t)(T + 2) * 64);
    __builtin_amdgcn_s_setprio(1);
#pragma unroll
    for (int fr = 0; fr < 4; ++fr)
#pragma unroll
      for (int nc = 0; nc < 2; ++nc)
#pragma unroll
        for (int ks = 0; ks < 2; ++ks)
          acc[4 + fr][2 + nc] = __builtin_amdgcn_mfma_f32_16x16x32_bf16(arHi[fr][ks], br[nc][ks],
                                                                        acc[4 + fr][2 + nc], 0, 0, 0);
    __builtin_amdgcn_s_setprio(0);
    if (T + 2 < nkt) {
      VMCNT4();
    } else {
      VMCNT0();
    }
    SBAR();

    if (T + 2 < nkt) STAGEH(b, 2, gB0 + (size_t)(T + 2) * 64);
    __builtin_amdgcn_s_setprio(1);
#pragma unroll
    for (int fr = 0; fr < 4; ++fr)
#pragma unroll
      for (int nc = 0; nc < 2; ++nc)
#pragma unroll
        for (int ks = 0; ks < 2; ++ks)
          acc[fr][2 + nc] = __builtin_amdgcn_mfma_f32_16x16x32_bf16(arLo[fr][ks], br[nc][ks],
                                                                    acc[fr][2 + nc], 0, 0, 0);
    __builtin_amdgcn_s_setprio(0);
    if (T + 1 < nkt) {
#pragma unroll
      for (int fr = 0; fr < 4; ++fr)
#pragma unroll
        for (int ks = 0; ks < 2; ++ks)
          arLo[fr][ks] = *reinterpret_cast<const bf16x8*>(bufAn + (fr * 2 + ks) * 512);
#pragma unroll
      for (int nc = 0; nc < 2; ++nc)
#pragma unroll
        for (int ks = 0; ks < 2; ++ks)
          br[nc][ks] = *reinterpret_cast<const bf16x8*>(bufBn + ((bf0 + nc) * 2 + ks) * 512);
    }
    SBAR();
  };

  for (int TT = 0; TT < nkt; TT += 2) {
    kbody(TT, 0);
    kbody(TT + 1, 1);
  }

  epi(acc, wm * 128 + l16 * 4, wn * 64 + l15);
}

// ---------------------------------------------------------------------------
// 128x256-tile GEMM core -- r11 version verbatim. BK=32, triple-buffered LDS
// (72 KB), counted vmcnt(3) ledger. Requires nkt >= 2.
// R14 NOTE: when called twice from one kernel, the CALLER must place
// VMCNT0+SBAR between the calls. The r13 post-timing race: call #1's 64
// epilogue global stores sit in the vmcnt queue when call #2's prologue runs
// vmcnt(3); in-order retirement across mixed stores+DMA-loads is only
// load-verified (m135), so vmcnt(3) could leave STAGE(0) loads unretired
// while tile-0 reads proceed. Draining to 0 at the boundary restores the
// single-call ledger exactly.
// ---------------------------------------------------------------------------
template <typename EPI>
__device__ __forceinline__ void gemm128x256(const u16* __restrict__ A, int lda,
                                            const u16* __restrict__ Bt, int ldb,
                                            int m0, int n0, int K, EPI&& epi) {
  __shared__ __align__(16) u16 lds[36864];  // 3 x [A 4096 | B 8192] u16 = 72 KB

  const int t = threadIdx.x;
  const int lane = t & 63;
  const int w = t >> 6;
  const int wm = w >> 2;    // 0..1 (m half: 64 rows)
  const int wn = w & 3;     // 0..3 (n quarter: 64 cols)
  const int l15 = lane & 15;
  const int l16 = lane >> 4;
  const int nkt = K >> 5;   // BK = 32

  f32x4 acc[4][4];
#pragma unroll
  for (int i = 0; i < 4; ++i)
#pragma unroll
    for (int j = 0; j < 4; ++j) acc[i][j] = {0.f, 0.f, 0.f, 0.f};

  const u16* gA = A + (size_t)(m0 + w * 16 + l15) * lda + l16 * 8;
  const u16* gB = Bt + (size_t)(n0 + w * 16 + l15) * ldb + l16 * 8;
  const size_t ldJB = (size_t)128 * ldb;

  auto STAGE = [&](int kbuf, int T) {
    const size_t koff = (size_t)T * 32;
    u16* base = lds + kbuf * 12288;
    gld_lds16(gA + koff, base + w * 512);                 // A rows 0..127
    gld_lds16(gB + koff, base + 4096 + w * 512);          // B rows 0..127
    gld_lds16(gB + koff + ldJB, base + 8192 + w * 512);   // B rows 128..255
  };

  STAGE(0, 0);
  STAGE(1, 1);
  VMCNT3();
  SBAR();

  int cb = 0;
  int sb = 2;
  for (int T = 0; T < nkt; ++T) {
    if (T + 2 < nkt) STAGE(sb, T + 2);

    const u16* bufA = lds + cb * 12288 + (wm * 4) * 512 + lane * 8;
    const u16* bufB = lds + cb * 12288 + 4096 + (wn * 4) * 512 + lane * 8;
    bf16x8 ar[4], br[4];
#pragma unroll
    for (int fr = 0; fr < 4; ++fr)
      ar[fr] = *reinterpret_cast<const bf16x8*>(bufA + fr * 512);
#pragma unroll
    for (int nc = 0; nc < 4; ++nc)
      br[nc] = *reinterpret_cast<const bf16x8*>(bufB + nc * 512);

    __builtin_amdgcn_s_setprio(1);
#pragma unroll
    for (int fr = 0; fr < 4; ++fr)
#pragma unroll
      for (int nc = 0; nc < 4; ++nc)
        acc[fr][nc] = __builtin_amdgcn_mfma_f32_16x16x32_bf16(ar[fr], br[nc],
                                                              acc[fr][nc], 0, 0, 0);
    __builtin_amdgcn_s_setprio(0);
    __builtin_amdgcn_sched_barrier(0);
    if (T + 2 < nkt) {
      VMCNT3();
    } else {
      VMCNT0();
    }
    SBAR();
    cb = (cb == 2) ? 0 : cb + 1;
    sb = (sb == 2) ? 0 : sb + 1;
  }

  epi(acc, wm * 64 + l16 * 4, wn * 64 + l15);
}

// ---------------------------------------------------------------------------
__global__ __launch_bounds__(256) void k_cvt_x(const float* __restrict__ x,
                                               u16* __restrict__ xb) {
  const int idx = (blockIdx.x * 256 + threadIdx.x) * 4;
  const float4 v = *reinterpret_cast<const float4*>(x + idx);
  ushort4 o;
  o.x = f2bf(v.x); o.y = f2bf(v.y); o.z = f2bf(v.z); o.w = f2bf(v.w);
  *reinterpret_cast<ushort4*>(xb + idx) = o;
}

// All three W [DIN][DOUT] fp32 -> Wt_all [3072][1024] bf16, one launch.
__global__ __launch_bounds__(256) void k_cvt_wt3(const float* __restrict__ Wq,
                                                 const float* __restrict__ Wk,
                                                 const float* __restrict__ Wv,
                                                 u16* __restrict__ Wt_all) {
  __shared__ u16 tile[64][65];
  const int sel = blockIdx.x >> 8;  // 0..2
  const int bc = blockIdx.x & 255;
  const float* W = (sel == 0) ? Wq : ((sel == 1) ? Wk : Wv);
  u16* Wt = Wt_all + ((size_t)sel << 20);
  const int tr0 = (bc >> 4) * 64;
  const int tc0 = (bc & 15) * 64;
  const int t = threadIdx.x;
  const int col = t & 63, rr = t >> 6;
#pragma unroll
  for (int p = 0; p < 16; ++p) {
    const int row = rr * 16 + p;
    tile[row][col] = f2bf(W[(size_t)(tr0 + row) * DOUT + tc0 + col]);
  }
  __syncthreads();
#pragma unroll
  for (int p = 0; p < 16; ++p) {
    const int row = rr * 16 + p;
    Wt[(size_t)(tc0 + row) * DIN + tr0 + col] = tile[col][row];
  }
}

// Fused QKV projection. 768 blocks, XCD-swizzled; n-tiles 0-7 -> qk row-major,
// 8-11 -> vT transposed.
__global__ __launch_bounds__(512, 2) void k_proj(const u16* __restrict__ xb,
                                                 const u16* __restrict__ Wt,
                                                 u16* __restrict__ qkb,
                                                 u16* __restrict__ vT) {
  const int wg = (blockIdx.x & 7) * 96 + (blockIdx.x >> 3);  // bijective, 768%8==0
  const int m0 = (wg / 12) * 256, n0 = (wg % 12) * 256;
  gemm256(xb, DIN, Wt, DIN, m0, n0, DIN,
          [&](const f32x4(&acc)[8][4], int r0, int c0) {
            if (n0 < 2 * DOUT) {
#pragma unroll
              for (int fr = 0; fr < 8; ++fr)
#pragma unroll
                for (int nc = 0; nc < 4; ++nc) {
                  const int r = m0 + r0 + fr * 16;
                  const int c = n0 + c0 + nc * 16;
#pragma unroll
                  for (int i = 0; i < 4; ++i)
                    qkb[(size_t)(r + i) * 2048 + c] = f2bf(acc[fr][nc][i]);
                }
            } else {
              const int b = m0 >> 11;
              const int sl = (m0 & (CTX - 1)) + r0;
              u16* C = vT + (size_t)b * DOUT * CTX;
#pragma unroll
              for (int fr = 0; fr < 8; ++fr)
#pragma unroll
                for (int nc = 0; nc < 4; ++nc) {
                  const int d = n0 - 2 * DOUT + c0 + nc * 16;
                  const int s = sl + fr * 16;
                  ushort4 o;
                  o.x = f2bf(acc[fr][nc][0]);
                  o.y = f2bf(acc[fr][nc][1]);
                  o.z = f2bf(acc[fr][nc][2]);
                  o.w = f2bf(acc[fr][nc][3]);
                  *reinterpret_cast<ushort4*>(C + (size_t)d * CTX + s) = o;
                }
            }
          });
}

// S[b][i][j] = (q.k)/32, lower-triangular 256x256 tiles (36 per batch)
__global__ __launch_bounds__(512, 2) void k_score(const u16* __restrict__ qkb,
                                                  float* __restrict__ S) {
  const int u = (blockIdx.x & 7) * 36 + (blockIdx.x >> 3);  // 288%8==0
  const int b = u / 36, v = u % 36;
  int it = 0;
  while ((it + 1) * (it + 2) / 2 <= v) ++it;
  const int jt = v - it * (it + 1) / 2;
  const u16* Aq = qkb + (size_t)b * CTX * 2048;
  float* C = S + ((size_t)b << 22);
  const int m0 = it * 256, n0 = jt * 256;
  gemm256(Aq, 2048, Aq + 1024, 2048, m0, n0, DOUT,
          [&](const f32x4(&acc)[8][4], int r0, int c0) {
#pragma unroll
            for (int fr = 0; fr < 8; ++fr)
#pragma unroll
              for (int nc = 0; nc < 4; ++nc) {
                const int r = m0 + r0 + fr * 16;
                const int c = n0 + c0 + nc * 16;
#pragma unroll
                for (int i = 0; i < 4; ++i)
                  C[(size_t)(r + i) * CTX + c] = acc[fr][nc][i] * 0.03125f;
              }
          });
}

// row softmax over S fp32, write P bf16 in place (row stride 4096 u16),
// full 2048 cols written (zeros above diagonal) so PV GEMM needs no masking.
__global__ __launch_bounds__(256) void k_softmax(float* __restrict__ Sws) {
  const int row = blockIdx.x;
  const int b = row >> 11, i = row & (CTX - 1);
  const float* srow = Sws + ((size_t)b << 22) + ((size_t)i << 11);
  u16* prow = (u16*)(Sws + ((size_t)b << 22)) + ((size_t)i << 12);
  const int t = threadIdx.x;
  const int j0 = t * 8;
  float vv[8];
  if (j0 <= i) {
    const float4 v0 = *reinterpret_cast<const float4*>(srow + j0);
    const float4 v1 = *reinterpret_cast<const float4*>(srow + j0 + 4);
    vv[0] = v0.x; vv[1] = v0.y; vv[2] = v0.z; vv[3] = v0.w;
    vv[4] = v1.x; vv[5] = v1.y; vv[6] = v1.z; vv[7] = v1.w;
  } else {
#pragma unroll
    for (int p = 0; p < 8; ++p) vv[p] = -3.0e38f;
  }
  float mx = -3.0e38f;
#pragma unroll
  for (int p = 0; p < 8; ++p) {
    vv[p] = (j0 + p <= i) ? vv[p] : -3.0e38f;
    mx = fmaxf(mx, vv[p]);
  }
#pragma unroll
  for (int off = 32; off > 0; off >>= 1) mx = fmaxf(mx, __shfl_xor(mx, off));
  __shared__ float redm[4], reds[4];
  const int lane = t & 63, wid = t >> 6;
  if (lane == 0) redm[wid] = mx;
  __syncthreads();
  mx = fmaxf(fmaxf(redm[0], redm[1]), fmaxf(redm[2], redm[3]));
  float e[8], s = 0.f;
#pragma unroll
  for (int p = 0; p < 8; ++p) {
    e[p] = __expf(vv[p] - mx);
    s += e[p];
  }
#pragma unroll
  for (int off = 32; off > 0; off >>= 1) s += __shfl_xor(s, off);
  if (lane == 0) reds[wid] = s;
  __syncthreads();  // orders row reads above before in-place writes below
  s = reds[0] + reds[1] + reds[2] + reds[3];
  const float inv = 1.0f / s;
  ushort4 o0, o1;
  o0.x = (j0 + 0 <= i) ? f2bf(e[0] * inv) : (u16)0;
  o0.y = (j0 + 1 <= i) ? f2bf(e[1] * inv) : (u16)0;
  o0.z = (j0 + 2 <= i) ? f2bf(e[2] * inv) : (u16)0;
  o0.w = (j0 + 3 <= i) ? f2bf(e[3] * inv) : (u16)0;
  o1.x = (j0 + 4 <= i) ? f2bf(e[4] * inv) : (u16)0;
  o1.y = (j0 + 5 <= i) ? f2bf(e[5] * inv) : (u16)0;
  o1.z = (j0 + 6 <= i) ? f2bf(e[6] * inv) : (u16)0;
  o1.w = (j0 + 7 <= i) ? f2bf(e[7] * inv) : (u16)0;
  *reinterpret_cast<ushort4*>(prow + j0) = o0;
  *reinterpret_cast<ushort4*>(prow + j0 + 4) = o1;
}

// out[b][i][d] = sum_j P[b][i][j] * V[b][j][d], causal K.
// Uniform folded bands: 256 blocks (8pp x 8b x 4nt); each block runs band
// it=15-pp (K=(16-pp)*128) then it=pp (K=(pp+1)*128) -- exactly 17 x 128-K
// per block => makespan == balanced. R14: VMCNT0+SBAR between the calls
// drains call #1's epilogue stores so call #2's counted vmcnt(3) ledger is
// sound (the r13 post-timing race).
__global__ __launch_bounds__(512, 4) void k_out(const float* __restrict__ Sws,
                                                const u16* __restrict__ vT,
                                                float* __restrict__ out) {
  const int idx = blockIdx.x;          // 256 = 8pp x 8b x 4nt
  const int pp = idx >> 5;             // 0..7
  const int b = (idx >> 2) & 7;
  const int nt = idx & 3;
  const u16* P = (const u16*)(Sws + ((size_t)b << 22));  // lda = 4096 u16
  const u16* Bt = vT + (size_t)b * DOUT * CTX;           // [D][S]
  float* C = out + (size_t)b * CTX * DOUT;
#pragma unroll 1
  for (int s = 0; s < 2; ++s) {
    const int it = s ? pp : (15 - pp);  // long band first
    const int m0 = it * 128, n0 = nt * 256;
    gemm128x256(P, 2 * CTX, Bt, CTX, m0, n0, (it + 1) * 128,
                [&](const f32x4(&acc)[4][4], int r0, int c0) {
#pragma unroll
                  for (int fr = 0; fr < 4; ++fr)
#pragma unroll
                    for (int nc = 0; nc < 4; ++nc) {
                      const int r = m0 + r0 + fr * 16;
                      const int c = n0 + c0 + nc * 16;
#pragma unroll
                      for (int i = 0; i < 4; ++i)
                        C[(size_t)(r + i) * DOUT + c] = acc[fr][nc][i];
                    }
                });
    VMCNT0();  // drain epilogue stores (+ any DMA) before the next call's
    SBAR();    // counted vmcnt; restores the verified single-call ledger
  }
}

// ---------------------------------------------------------------------------
extern "C" void kernel_launch(void* const* d_in, const int* in_sizes, int n_in,
                              void* d_out, int out_size, void* d_ws, size_t ws_size,
                              hipStream_t stream) {
  (void)in_sizes; (void)n_in; (void)out_size; (void)ws_size;
  const float* x = (const float*)d_in[0];
  const float* Wq = (const float*)d_in[1];
  const float* Wk = (const float*)d_in[2];
  const float* Wv = (const float*)d_in[3];
  float* out = (float*)d_out;
  uint8_t* ws = (uint8_t*)d_ws;

  // ws layout (224 MB):
  //   [0,128M): S fp32 [8][2048][2048] (P bf16 written in place by softmax)
  //     xb bf16 (32MB) + Wt_all (6MB) overlap S -- dead before k_score runs
  //   [128M,192M): qkb bf16 [8][2048][2048] (q cols 0..1023, k cols 1024..2047)
  //   [192M,224M): vT bf16 [8][1024][2048]
  float* S = (float*)ws;
  u16* xb = (u16*)ws;
  u16* Wt_all = (u16*)(ws + 33554432ull);  // [3072][1024]: q|k|v
  u16* qkb = (u16*)(ws + 134217728ull);
  u16* vT = (u16*)(ws + 201326592ull);

  k_cvt_x<<<16384, 256, 0, stream>>>(x, xb);
  k_cvt_wt3<<<768, 256, 0, stream>>>(Wq, Wk, Wv, Wt_all);
  k_proj<<<768, 512, 0, stream>>>(xb, Wt_all, qkb, vT);
  k_score<<<288, 512, 0, stream>>>(qkb, S);
  k_softmax<<<NB * CTX, 256, 0, stream>>>(S);
  k_out<<<256, 512, 0, stream>>>(S, vT, out);
}